// Round 1
// baseline (206.871 us; speedup 1.0000x reference)
//
#include <hip/hip_runtime.h>

#define Bz 4
#define Tz 4096
#define Ez 1024
#define Hz 16
#define Sz 64
#define Dz 64
#define MTz (Bz*Tz)   // 16384

using f32x4  = __attribute__((ext_vector_type(4))) float;
using short8 = __attribute__((ext_vector_type(8))) short;

__device__ __forceinline__ unsigned short f2bf(float f){
  unsigned u = __builtin_bit_cast(unsigned, f);
  u = u + 0x7FFFu + ((u >> 16) & 1u);
  return (unsigned short)(u >> 16);
}

#define GLL16(gp, lp) __builtin_amdgcn_global_load_lds( \
    (const __attribute__((address_space(1))) unsigned int*)(gp), \
    (__attribute__((address_space(3))) unsigned int*)(lp), 16, 0, 0)

// ---------------- K1: a_state [H,B,S], M[h]=C_w[h]@sm[h], smB=bf16(sm) ----------------
__global__ __launch_bounds__(256) void k1_pre(const float* __restrict__ state,
                                              const float* __restrict__ A_w,
                                              const float* __restrict__ A_b,
                                              const float* __restrict__ C_w,
                                              const float* __restrict__ sm,
                                              float* __restrict__ a_state,
                                              float* __restrict__ Mh,
                                              unsigned short* __restrict__ smB){
  const int h = blockIdx.x, tid = threadIdx.x;
  { // a_state[h][b][s] = A_w[h][s][:] . state[h][b][:] + A_b[h][s]
    const int b = tid >> 6, s = tid & 63;
    const float* aw = A_w + (size_t)(h*64 + s)*64;
    const float* st = state + (size_t)(h*4 + b)*64;
    float acc = A_b[h*64 + s];
    #pragma unroll 8
    for (int j = 0; j < 64; ++j) acc += aw[j]*st[j];
    a_state[(h*4 + b)*64 + s] = acc;
  }
  // smB
  for (int r = 0; r < 16; ++r){
    int o = r*256 + tid;
    smB[h*4096 + o] = f2bf(sm[h*4096 + o]);
  }
  // M[h][d][dp] = sum_s C_w[h][d][s] * sm[h][s][dp]
  for (int r = 0; r < 16; ++r){
    int o = r*256 + tid;
    int d = o >> 6, dp = o & 63;
    const float* cw  = C_w + (size_t)(h*64 + d)*64;
    const float* smh = sm + (size_t)h*4096;
    float acc = 0.f;
    #pragma unroll 8
    for (int s = 0; s < 64; ++s) acc += cw[s]*smh[s*64 + dp];
    Mh[h*4096 + o] = acc;
  }
}

// ---------------- K2: W_eff=(Wo@BDiag(M)) -> bf16 ; bias_f[b][f]=C_w@a_state+C_b ------
__global__ __launch_bounds__(256) void k2_pre(const float* __restrict__ Wo,
                                              const float* __restrict__ Mh,
                                              const float* __restrict__ C_w,
                                              const float* __restrict__ C_b,
                                              const float* __restrict__ a_state,
                                              unsigned short* __restrict__ Wb,
                                              float* __restrict__ bias_f){
  const int blk = blockIdx.x, tid = threadIdx.x;
  if (blk < 4096){
    int idx = blk*256 + tid;
    int e = idx >> 10, c = idx & 1023;
    int h = c >> 6, dp = c & 63;
    const float* wo = Wo + (size_t)e*1024 + h*64;
    const float* m  = Mh + (size_t)h*4096 + dp;
    float acc = 0.f;
    #pragma unroll 8
    for (int d = 0; d < 64; ++d) acc += wo[d]*m[d*64];
    Wb[idx] = f2bf(acc);
  } else {
    for (int r = 0; r < 16; ++r){
      int o = r*256 + tid;          // [b][f]
      int b = o >> 10, f = o & 1023;
      int h = f >> 6, d = f & 63;
      const float* cw = C_w + (size_t)(h*64 + d)*64;
      const float* as = a_state + (size_t)(h*4 + b)*64;
      float acc = C_b[h*64 + d];
      #pragma unroll 8
      for (int s = 0; s < 64; ++s) acc += cw[s]*as[s];
      bias_f[o] = acc;
    }
  }
}

// ---------------- K3: const[b][e] = Wo[e][:] . bias_f[b][:] + bo[e] -------------------
__global__ __launch_bounds__(256) void k3_const(const float* __restrict__ Wo,
                                                const float* __restrict__ bo,
                                                const float* __restrict__ bias_f,
                                                float* __restrict__ constb){
  int idx = blockIdx.x*256 + threadIdx.x;  // 16 blocks -> 4096
  int b = idx >> 10, e = idx & 1023;
  const float4* wo = (const float4*)(Wo + (size_t)e*1024);
  const float4* bf = (const float4*)(bias_f + (size_t)b*1024);
  float acc = bo[e];
  for (int f4 = 0; f4 < 256; ++f4){
    float4 w = wo[f4], v = bf[f4];
    acc += w.x*v.x + w.y*v.y + w.z*v.z + w.w*v.w;
  }
  constb[idx] = acc;
}

// ---------------- K4: new_state (MFMA, K=64) + emit xb=bf16(x) ------------------------
// grid: b(4) x h(16) x tb(32) = 2048 blocks, 256 thr (4 waves), tile 128(t) x 64(s)
__global__ __launch_bounds__(256) void k4_ns(const float* __restrict__ x,
                                             const unsigned short* __restrict__ smB,
                                             const float* __restrict__ a_state,
                                             unsigned short* __restrict__ xb,
                                             float* __restrict__ out2){
  __shared__ alignas(16) unsigned short Xs[128*72];
  __shared__ alignas(16) unsigned short Ss[64*72];
  const int lin = blockIdx.x;
  const int tb = lin & 31, h = (lin >> 5) & 15, b = lin >> 9;
  const int tid = threadIdx.x;
  const int lane = tid & 63, w = tid >> 6;
  const int l15 = lane & 15, l4 = lane >> 4;

  { // stage smB[h] -> Ss (row stride 72)
    const uint2* src = (const uint2*)(smB + (size_t)h*4096); // 1024 x uint2(4 elems)
    #pragma unroll
    for (int it = 0; it < 2; ++it){
      int c = it*512 + tid*2;              // 8-elem chunk index*2? -> use 4-elem chunks
      // c in [0,1024): chunk of 4 elems
      int s = c >> 4, k4 = c & 15;
      uint2 v0 = src[c], v1 = src[c+1];
      *(uint2*)(&Ss[s*72 + k4*4])     = v0;
      *(uint2*)(&Ss[s*72 + k4*4 + 4]) = v1;
    }
  }
  { // stage x slice -> Xs bf16 (stride 72) and xb global
    const int row0 = b*Tz + tb*128;        // global m row
    #pragma unroll
    for (int it = 0; it < 8; ++it){
      int c = it*256 + tid;                // 2048 float4 chunks
      int r = c >> 4, c4 = c & 15;
      const float4 v = *(const float4*)(x + (size_t)(row0 + r)*1024 + h*64 + c4*4);
      unsigned lo = (unsigned)f2bf(v.x) | ((unsigned)f2bf(v.y) << 16);
      unsigned hi = (unsigned)f2bf(v.z) | ((unsigned)f2bf(v.w) << 16);
      uint2 pk = make_uint2(lo, hi);
      *(uint2*)(&Xs[r*72 + c4*4]) = pk;
      *(uint2*)(xb + (size_t)(row0 + r)*1024 + h*64 + c4*4) = pk;
    }
  }
  __syncthreads();

  f32x4 acc[2][4];
  #pragma unroll
  for (int j = 0; j < 4; ++j){
    float bias = a_state[(h*4 + b)*64 + j*16 + l15];
    #pragma unroll
    for (int i = 0; i < 2; ++i){
      acc[i][j][0] = bias; acc[i][j][1] = bias; acc[i][j][2] = bias; acc[i][j][3] = bias;
    }
  }
  #pragma unroll
  for (int kk = 0; kk < 2; ++kk){
    short8 a[2], bb[4];
    #pragma unroll
    for (int i = 0; i < 2; ++i)
      a[i] = *(const short8*)(&Xs[(w*32 + i*16 + l15)*72 + kk*32 + l4*8]);
    #pragma unroll
    for (int j = 0; j < 4; ++j)
      bb[j] = *(const short8*)(&Ss[(j*16 + l15)*72 + kk*32 + l4*8]);
    #pragma unroll
    for (int i = 0; i < 2; ++i)
      #pragma unroll
      for (int j = 0; j < 4; ++j)
        acc[i][j] = __builtin_amdgcn_mfma_f32_16x16x32_bf16(a[i], bb[j], acc[i][j], 0, 0, 0);
  }
  // store: out2[h*1048576 + (b*4096 + t)*64 + s]
  const size_t base = (size_t)h*1048576 + ((size_t)b*4096 + tb*128)*64;
  #pragma unroll
  for (int i = 0; i < 2; ++i)
    #pragma unroll
    for (int j = 0; j < 4; ++j){
      int s = j*16 + l15;
      #pragma unroll
      for (int q = 0; q < 4; ++q){
        int tr = w*32 + i*16 + l4*4 + q;
        out2[base + (size_t)tr*64 + s] = acc[i][j][q];
      }
    }
}

// ---------------- K5: out = xb @ Wb^T + const  (128x128 tile, BK=32, gll16) -----------
__global__ __launch_bounds__(256) void k5_gemm(const unsigned short* __restrict__ xb,
                                               const unsigned short* __restrict__ Wb,
                                               const float* __restrict__ constb,
                                               float* __restrict__ out){
  __shared__ alignas(16) unsigned short As[128*32];
  __shared__ alignas(16) unsigned short Bs[128*32];
  const int blk = blockIdx.x;
  const int swz = (blk & 7)*128 + (blk >> 3);     // XCD-contiguous chunks (1024%8==0)
  const int bm = (swz >> 3)*128, bn = (swz & 7)*128;
  const int tid = threadIdx.x;
  const int lane = tid & 63, w = tid >> 6;
  const int l15 = lane & 15, l4 = lane >> 4;
  const int wr = w >> 1, wc = w & 1;

  // staging source pointers (per-lane), LDS dests (wave-uniform)
  const unsigned short* gA0 = xb + (size_t)(bm + w*32 + (lane >> 2))*1024 + (lane & 3)*8;
  const unsigned short* gA1 = gA0 + (size_t)16*1024;
  const unsigned short* gB0 = Wb + (size_t)(bn + w*32 + (lane >> 2))*1024 + (lane & 3)*8;
  const unsigned short* gB1 = gB0 + (size_t)16*1024;
  unsigned short* la0 = &As[(w*2 + 0)*512];
  unsigned short* la1 = &As[(w*2 + 1)*512];
  unsigned short* lb0 = &Bs[(w*2 + 0)*512];
  unsigned short* lb1 = &Bs[(w*2 + 1)*512];

  f32x4 acc[4][4] = {};

  for (int kt = 0; kt < 32; ++kt){
    GLL16(gA0, la0); GLL16(gA1, la1);
    GLL16(gB0, lb0); GLL16(gB1, lb1);
    gA0 += 32; gA1 += 32; gB0 += 32; gB1 += 32;
    __syncthreads();
    short8 af[4], bf[4];
    #pragma unroll
    for (int i = 0; i < 4; ++i)
      af[i] = *(const short8*)(&As[(wr*64 + i*16 + l15)*32 + l4*8]);
    #pragma unroll
    for (int j = 0; j < 4; ++j)
      bf[j] = *(const short8*)(&Bs[(wc*64 + j*16 + l15)*32 + l4*8]);
    #pragma unroll
    for (int i = 0; i < 4; ++i)
      #pragma unroll
      for (int j = 0; j < 4; ++j)
        acc[i][j] = __builtin_amdgcn_mfma_f32_16x16x32_bf16(af[i], bf[j], acc[i][j], 0, 0, 0);
    __syncthreads();
  }

  const int bb = bm >> 12;  // batch index
  #pragma unroll
  for (int j = 0; j < 4; ++j){
    int n = bn + wc*64 + j*16 + l15;
    float cv = constb[bb*1024 + n];
    #pragma unroll
    for (int i = 0; i < 4; ++i){
      int rbase = bm + wr*64 + i*16 + l4*4;
      #pragma unroll
      for (int q = 0; q < 4; ++q)
        out[(size_t)(rbase + q)*1024 + n] = acc[i][j][q] + cv;
    }
  }
}

extern "C" void kernel_launch(void* const* d_in, const int* in_sizes, int n_in,
                              void* d_out, int out_size, void* d_ws, size_t ws_size,
                              hipStream_t stream){
  const float* x     = (const float*)d_in[0];
  const float* state = (const float*)d_in[1];
  const float* A_w   = (const float*)d_in[2];
  const float* A_b   = (const float*)d_in[3];
  const float* C_w   = (const float*)d_in[4];
  const float* C_b   = (const float*)d_in[5];
  const float* sm    = (const float*)d_in[6];
  const float* Wo    = (const float*)d_in[7];
  const float* bo    = (const float*)d_in[8];
  float* out  = (float*)d_out;
  float* out2 = out + (size_t)MTz*Ez;

  char* ws = (char*)d_ws;
  float* a_state          = (float*)(ws + 0);          //  16 KiB
  float* Mh               = (float*)(ws + 16384);      // 256 KiB
  float* bias_f           = (float*)(ws + 278528);     //  16 KiB
  float* constb           = (float*)(ws + 294912);     //  16 KiB
  unsigned short* smB     = (unsigned short*)(ws + 311296);   // 128 KiB
  unsigned short* Wb      = (unsigned short*)(ws + 442368);   //   2 MiB
  unsigned short* xb      = (unsigned short*)(ws + 2539520);  //  32 MiB

  k1_pre<<<16, 256, 0, stream>>>(state, A_w, A_b, C_w, sm, a_state, Mh, smB);
  k2_pre<<<4097, 256, 0, stream>>>(Wo, Mh, C_w, C_b, a_state, Wb, bias_f);
  k3_const<<<16, 256, 0, stream>>>(Wo, bo, bias_f, constb);
  k4_ns<<<2048, 256, 0, stream>>>(x, smB, a_state, xb, out2);
  k5_gemm<<<1024, 256, 0, stream>>>(xb, Wb, constb, out);
}

// Round 2
// 129.856 us; speedup vs baseline: 1.5931x; 1.5931x over previous
//
#include <hip/hip_runtime.h>

#define Bz 4
#define Tz 4096
#define Ez 1024
#define Hz 16
#define Sz 64
#define Dz 64
#define MTz (Bz*Tz)   // 16384

using f32x4  = __attribute__((ext_vector_type(4))) float;
using short8 = __attribute__((ext_vector_type(8))) short;

__device__ __forceinline__ unsigned f2bf(float f){
  unsigned u = __builtin_bit_cast(unsigned, f);
  u = u + 0x7FFFu + ((u >> 16) & 1u);
  return (u >> 16);
}

#define GLL16(gp, lp) __builtin_amdgcn_global_load_lds( \
    (const __attribute__((address_space(1))) unsigned int*)(gp), \
    (__attribute__((address_space(3))) unsigned int*)(lp), 16, 0, 0)

// ---------------- K1: Mh[h]=C_w[h]@sm[h] (64 blocks), smB=bf16(sm), a_state ----------
__global__ __launch_bounds__(256) void k1_pre(const float* __restrict__ state,
                                              const float* __restrict__ A_w,
                                              const float* __restrict__ A_b,
                                              const float* __restrict__ C_w,
                                              const float* __restrict__ sm,
                                              float* __restrict__ a_state,
                                              float* __restrict__ Mh,
                                              unsigned short* __restrict__ smB){
  const int blk = blockIdx.x, tid = threadIdx.x;
  const int h = blk >> 2, q4 = blk & 3;
  { // Mh[h][d][dp] = sum_s C_w[h][d][s]*sm[h][s][dp], quarter of d-rows per block
    const int d = q4*16 + (tid >> 4), dp0 = (tid & 15)*4;
    const float* cw  = C_w + (size_t)(h*64 + d)*64;
    const float* smh = sm + (size_t)h*4096 + dp0;
    float ax=0.f, ay=0.f, az=0.f, aw=0.f;
    #pragma unroll 8
    for (int s = 0; s < 64; ++s){
      float c = cw[s];
      float4 m4 = *(const float4*)&smh[s*64];
      ax += c*m4.x; ay += c*m4.y; az += c*m4.z; aw += c*m4.w;
    }
    *(float4*)&Mh[(size_t)h*4096 + d*64 + dp0] = make_float4(ax,ay,az,aw);
  }
  { // smB cast: 1024 elems per block
    int gi = blk*1024 + tid*4;
    float4 v = *(const float4*)&sm[gi];
    uint2 pk = make_uint2(f2bf(v.x) | (f2bf(v.y)<<16), f2bf(v.z) | (f2bf(v.w)<<16));
    *(uint2*)&smB[gi] = pk;
  }
  if (q4 == 0){ // a_state[h][b][s] = A_w[h][s][:] . state[h][b][:] + A_b[h][s]
    const int b = tid >> 6, s = tid & 63;
    const float* aw = A_w + (size_t)(h*64 + s)*64;
    const float* st = state + (size_t)(h*4 + b)*64;
    float a0=A_b[h*64+s], a1=0.f, a2=0.f, a3=0.f;
    #pragma unroll 4
    for (int j = 0; j < 64; j += 4){
      a0 += aw[j]*st[j]; a1 += aw[j+1]*st[j+1];
      a2 += aw[j+2]*st[j+2]; a3 += aw[j+3]*st[j+3];
    }
    a_state[(h*4 + b)*64 + s] = (a0+a1)+(a2+a3);
  }
}

// ---------------- K2: Wb=bf16(Wo@BDiag(Mh)) (1024 blocks) ; bias_f (16 blocks) -------
__global__ __launch_bounds__(256) void k2_pre(const float* __restrict__ Wo,
                                              const float* __restrict__ Mh,
                                              const float* __restrict__ C_w,
                                              const float* __restrict__ C_b,
                                              const float* __restrict__ a_state,
                                              unsigned short* __restrict__ Wb,
                                              float* __restrict__ bias_f){
  const int blk = blockIdx.x, tid = threadIdx.x;
  if (blk < 1024){
    const int e = blk, h = tid >> 4, dp0 = (tid & 15)*4;
    const float* wo = Wo + (size_t)e*1024 + h*64;
    const float* mh = Mh + (size_t)h*4096 + dp0;
    float ax=0.f, ay=0.f, az=0.f, aw=0.f;
    #pragma unroll 8
    for (int d = 0; d < 64; ++d){
      float c = wo[d];
      float4 m4 = *(const float4*)&mh[d*64];
      ax += c*m4.x; ay += c*m4.y; az += c*m4.z; aw += c*m4.w;
    }
    uint2 pk = make_uint2(f2bf(ax) | (f2bf(ay)<<16), f2bf(az) | (f2bf(aw)<<16));
    *(uint2*)&Wb[(size_t)e*1024 + h*64 + dp0] = pk;
  } else {
    int o = (blk - 1024)*256 + tid;       // [b][f]
    int b = o >> 10, f = o & 1023;
    int h = f >> 6, d = f & 63;
    const float* cw = C_w + (size_t)(h*64 + d)*64;
    const float* as = a_state + (size_t)(h*4 + b)*64;
    float a0=C_b[h*64+d], a1=0.f, a2=0.f, a3=0.f;
    #pragma unroll 4
    for (int s = 0; s < 64; s += 4){
      a0 += cw[s]*as[s]; a1 += cw[s+1]*as[s+1];
      a2 += cw[s+2]*as[s+2]; a3 += cw[s+3]*as[s+3];
    }
    bias_f[o] = (a0+a1)+(a2+a3);
  }
}

// ---------------- K3: const[b][e] = Wo[e][:] . bias_f[b][:] + bo[e]  (64 blocks) -----
__global__ __launch_bounds__(64) void k3_const(const float* __restrict__ Wo,
                                               const float* __restrict__ bo,
                                               const float* __restrict__ bias_f,
                                               float* __restrict__ constb){
  const int blk = blockIdx.x, tid = threadIdx.x;
  const int b = blk >> 4, e = (blk & 15)*64 + tid;
  const float4* wo = (const float4*)(Wo + (size_t)e*1024);
  const float4* bf = (const float4*)(bias_f + (size_t)b*1024);
  float ax=0.f, ay=0.f, az=0.f, aw=0.f;
  for (int f4 = 0; f4 < 256; ++f4){
    float4 w = wo[f4], v = bf[f4];
    ax += w.x*v.x; ay += w.y*v.y; az += w.z*v.z; aw += w.w*v.w;
  }
  constb[b*1024 + e] = bo[e] + ((ax+ay)+(az+aw));
}

// ---------------- K4: new_state (MFMA, swapped operands) + emit xb=bf16(x) -----------
// grid: b(4) x h(16) x tb(32) = 2048 blocks, 256 thr, tile 128(t) x 64(s)
__global__ __launch_bounds__(256) void k4_ns(const float* __restrict__ x,
                                             const unsigned short* __restrict__ smB,
                                             const float* __restrict__ a_state,
                                             unsigned short* __restrict__ xb,
                                             float* __restrict__ out2){
  __shared__ alignas(16) unsigned short Xs[128*72];
  __shared__ alignas(16) unsigned short Ss[64*72];
  const int lin = blockIdx.x;
  const int tb = lin & 31, h = (lin >> 5) & 15, b = lin >> 9;
  const int tid = threadIdx.x;
  const int lane = tid & 63, w = tid >> 6;
  const int l15 = lane & 15, l4 = lane >> 4;

  { // stage smB[h] -> Ss (row stride 72 shorts), 16B granules
    const unsigned short* src = smB + (size_t)h*4096;
    #pragma unroll
    for (int cc = 0; cc < 2; ++cc){
      int c = tid*2 + cc;                  // 512 cells of 8 shorts
      int s = c >> 3, seg = c & 7;
      *(uint4*)&Ss[s*72 + seg*8] = *(const uint4*)&src[s*64 + seg*8];
    }
  }
  { // stage x slice -> Xs bf16 (stride 72) and xb global (16B granules)
    const int row0 = b*Tz + tb*128;
    #pragma unroll
    for (int it = 0; it < 4; ++it){
      int id = it*256 + tid;               // 1024 chunks of 8 floats
      int r = id >> 3, c8 = id & 7;
      const float* px = x + (size_t)(row0 + r)*1024 + h*64 + c8*8;
      float4 v0 = *(const float4*)px, v1 = *(const float4*)(px + 4);
      uint4 pk;
      pk.x = f2bf(v0.x) | (f2bf(v0.y)<<16);
      pk.y = f2bf(v0.z) | (f2bf(v0.w)<<16);
      pk.z = f2bf(v1.x) | (f2bf(v1.y)<<16);
      pk.w = f2bf(v1.z) | (f2bf(v1.w)<<16);
      *(uint4*)&Xs[r*72 + c8*8] = pk;
      *(uint4*)(xb + (size_t)(row0 + r)*1024 + h*64 + c8*8) = pk;
    }
  }
  __syncthreads();

  // acc[i][j]: swapped layout -> D rows = s (regs), D cols = t (l15)
  f32x4 acc[2][4];
  #pragma unroll
  for (int j = 0; j < 4; ++j){
    float4 as4 = *(const float4*)&a_state[(h*4 + b)*64 + j*16 + l4*4];
    f32x4 a0; a0[0]=as4.x; a0[1]=as4.y; a0[2]=as4.z; a0[3]=as4.w;
    acc[0][j] = a0; acc[1][j] = a0;
  }
  #pragma unroll
  for (int kk = 0; kk < 2; ++kk){
    short8 a[2], bb[4];
    #pragma unroll
    for (int i = 0; i < 2; ++i)
      a[i] = *(const short8*)(&Xs[(w*32 + i*16 + l15)*72 + kk*32 + l4*8]);
    #pragma unroll
    for (int j = 0; j < 4; ++j)
      bb[j] = *(const short8*)(&Ss[(j*16 + l15)*72 + kk*32 + l4*8]);
    #pragma unroll
    for (int i = 0; i < 2; ++i)
      #pragma unroll
      for (int j = 0; j < 4; ++j)
        acc[i][j] = __builtin_amdgcn_mfma_f32_16x16x32_bf16(bb[j], a[i], acc[i][j], 0, 0, 0);
  }
  // store: out2[h][b][t][s], thread writes float4 along s
  const size_t base = (size_t)h*1048576 + ((size_t)b*4096 + tb*128)*64;
  #pragma unroll
  for (int i = 0; i < 2; ++i)
    #pragma unroll
    for (int j = 0; j < 4; ++j){
      float4 o = make_float4(acc[i][j][0], acc[i][j][1], acc[i][j][2], acc[i][j][3]);
      *(float4*)(out2 + base + (size_t)(w*32 + i*16 + l15)*64 + j*16 + l4*4) = o;
    }
}

// ---------------- K5: out = xb @ Wb^T + const  (128x128, gll16, XOR-swizzled LDS) ----
__global__ __launch_bounds__(256) void k5_gemm(const unsigned short* __restrict__ xb,
                                               const unsigned short* __restrict__ Wb,
                                               const float* __restrict__ constb,
                                               float* __restrict__ out){
  __shared__ alignas(16) unsigned short As[128*32];
  __shared__ alignas(16) unsigned short Bs[128*32];
  const int blk = blockIdx.x;
  const int swz = (blk & 7)*128 + (blk >> 3);     // XCD-contiguous chunks (1024%8==0)
  const int bm = (swz >> 3)*128, bn = (swz & 7)*128;
  const int tid = threadIdx.x;
  const int lane = tid & 63, w = tid >> 6;
  const int l15 = lane & 15, l4 = lane >> 4;
  const int wr = w >> 1, wc = w & 1;

  // staging: lane handles row = base + (lane>>2), logical seg permuted by row&3.
  const int srow = lane >> 2;
  const int sseg = (lane & 3) ^ (srow & 3);       // inverse-swizzled global source
  const unsigned short* gA0 = xb + (size_t)(bm + w*32 + srow)*1024 + sseg*8;
  const unsigned short* gA1 = gA0 + (size_t)16*1024;
  const unsigned short* gB0 = Wb + (size_t)(bn + w*32 + srow)*1024 + sseg*8;
  const unsigned short* gB1 = gB0 + (size_t)16*1024;
  unsigned short* la0 = &As[(w*2 + 0)*512];
  unsigned short* la1 = &As[(w*2 + 1)*512];
  unsigned short* lb0 = &Bs[(w*2 + 0)*512];
  unsigned short* lb1 = &Bs[(w*2 + 1)*512];

  f32x4 acc[4][4] = {};

  for (int kt = 0; kt < 32; ++kt){
    GLL16(gA0, la0); GLL16(gA1, la1);
    GLL16(gB0, lb0); GLL16(gB1, lb1);
    gA0 += 32; gA1 += 32; gB0 += 32; gB1 += 32;
    __syncthreads();
    short8 af[4], bf[4];
    #pragma unroll
    for (int i = 0; i < 4; ++i){
      int row = wr*64 + i*16 + l15;
      af[i] = *(const short8*)(&As[row*32 + ((l4 ^ (l15 & 3))*8)]);
    }
    #pragma unroll
    for (int j = 0; j < 4; ++j){
      int row = wc*64 + j*16 + l15;
      bf[j] = *(const short8*)(&Bs[row*32 + ((l4 ^ (l15 & 3))*8)]);
    }
    #pragma unroll
    for (int i = 0; i < 4; ++i)
      #pragma unroll
      for (int j = 0; j < 4; ++j)
        acc[i][j] = __builtin_amdgcn_mfma_f32_16x16x32_bf16(bf[j], af[i], acc[i][j], 0, 0, 0);
    __syncthreads();
  }

  // swapped D: col(l15)=t within i-block, rows(l4*4+q)=e within j-block
  const int bb = bm >> 12;  // batch index
  #pragma unroll
  for (int j = 0; j < 4; ++j){
    int n0 = bn + wc*64 + j*16 + l4*4;
    float4 cv = *(const float4*)&constb[bb*1024 + n0];
    #pragma unroll
    for (int i = 0; i < 4; ++i){
      int t = bm + wr*64 + i*16 + l15;
      float4 o = make_float4(acc[i][j][0] + cv.x, acc[i][j][1] + cv.y,
                             acc[i][j][2] + cv.z, acc[i][j][3] + cv.w);
      *(float4*)(out + (size_t)t*1024 + n0) = o;
    }
  }
}

extern "C" void kernel_launch(void* const* d_in, const int* in_sizes, int n_in,
                              void* d_out, int out_size, void* d_ws, size_t ws_size,
                              hipStream_t stream){
  const float* x     = (const float*)d_in[0];
  const float* state = (const float*)d_in[1];
  const float* A_w   = (const float*)d_in[2];
  const float* A_b   = (const float*)d_in[3];
  const float* C_w   = (const float*)d_in[4];
  const float* C_b   = (const float*)d_in[5];
  const float* sm    = (const float*)d_in[6];
  const float* Wo    = (const float*)d_in[7];
  const float* bo    = (const float*)d_in[8];
  float* out  = (float*)d_out;
  float* out2 = out + (size_t)MTz*Ez;

  char* ws = (char*)d_ws;
  float* a_state          = (float*)(ws + 0);          //  16 KiB
  float* Mh               = (float*)(ws + 16384);      // 256 KiB
  float* bias_f           = (float*)(ws + 278528);     //  16 KiB
  float* constb           = (float*)(ws + 294912);     //  16 KiB
  unsigned short* smB     = (unsigned short*)(ws + 311296);   // 128 KiB
  unsigned short* Wb      = (unsigned short*)(ws + 442368);   //   2 MiB
  unsigned short* xb      = (unsigned short*)(ws + 2539520);  //  32 MiB

  k1_pre<<<64, 256, 0, stream>>>(state, A_w, A_b, C_w, sm, a_state, Mh, smB);
  k2_pre<<<1040, 256, 0, stream>>>(Wo, Mh, C_w, C_b, a_state, Wb, bias_f);
  k3_const<<<64, 64, 0, stream>>>(Wo, bo, bias_f, constb);
  k4_ns<<<2048, 256, 0, stream>>>(x, smB, a_state, xb, out2);
  k5_gemm<<<1024, 256, 0, stream>>>(xb, Wb, constb, out);
}

// Round 3
// 119.140 us; speedup vs baseline: 1.7364x; 1.0899x over previous
//
#include <hip/hip_runtime.h>

#define Bz 4
#define Tz 4096
#define Ez 1024
#define Hz 16
#define Sz 64
#define Dz 64
#define MTz (Bz*Tz)   // 16384

using f32x4  = __attribute__((ext_vector_type(4))) float;
using short8 = __attribute__((ext_vector_type(8))) short;

__device__ __forceinline__ unsigned f2bf(float f){
  unsigned u = __builtin_bit_cast(unsigned, f);
  u = u + 0x7FFFu + ((u >> 16) & 1u);
  return (u >> 16);
}

#define GLL16(gp, lp) __builtin_amdgcn_global_load_lds( \
    (const __attribute__((address_space(1))) unsigned int*)(gp), \
    (__attribute__((address_space(3))) unsigned int*)(lp), 16, 0, 0)

// ---------------- K1: Mh[h]=C_w[h]@sm[h] (64 blocks), smB=bf16(sm), a_state ----------
__global__ __launch_bounds__(256) void k1_pre(const float* __restrict__ state,
                                              const float* __restrict__ A_w,
                                              const float* __restrict__ A_b,
                                              const float* __restrict__ C_w,
                                              const float* __restrict__ sm,
                                              float* __restrict__ a_state,
                                              float* __restrict__ Mh,
                                              unsigned short* __restrict__ smB){
  const int blk = blockIdx.x, tid = threadIdx.x;
  const int h = blk >> 2, q4 = blk & 3;
  { // Mh[h][d][dp] = sum_s C_w[h][d][s]*sm[h][s][dp], quarter of d-rows per block
    const int d = q4*16 + (tid >> 4), dp0 = (tid & 15)*4;
    const float* cw  = C_w + (size_t)(h*64 + d)*64;
    const float* smh = sm + (size_t)h*4096 + dp0;
    float ax=0.f, ay=0.f, az=0.f, aw=0.f;
    #pragma unroll 8
    for (int s = 0; s < 64; ++s){
      float c = cw[s];
      float4 m4 = *(const float4*)&smh[s*64];
      ax += c*m4.x; ay += c*m4.y; az += c*m4.z; aw += c*m4.w;
    }
    *(float4*)&Mh[(size_t)h*4096 + d*64 + dp0] = make_float4(ax,ay,az,aw);
  }
  { // smB cast: 1024 elems per block
    int gi = blk*1024 + tid*4;
    float4 v = *(const float4*)&sm[gi];
    uint2 pk = make_uint2(f2bf(v.x) | (f2bf(v.y)<<16), f2bf(v.z) | (f2bf(v.w)<<16));
    *(uint2*)&smB[gi] = pk;
  }
  if (q4 == 0){ // a_state[h][b][s] = A_w[h][s][:] . state[h][b][:] + A_b[h][s]
    const int b = tid >> 6, s = tid & 63;
    const float* aw = A_w + (size_t)(h*64 + s)*64;
    const float* st = state + (size_t)(h*4 + b)*64;
    float a0=A_b[h*64+s], a1=0.f, a2=0.f, a3=0.f;
    #pragma unroll 4
    for (int j = 0; j < 64; j += 4){
      a0 += aw[j]*st[j]; a1 += aw[j+1]*st[j+1];
      a2 += aw[j+2]*st[j+2]; a3 += aw[j+3]*st[j+3];
    }
    a_state[(h*4 + b)*64 + s] = (a0+a1)+(a2+a3);
  }
}

// ---------------- K2: Wb=bf16(Wo@BDiag(Mh)) (1024 blocks) ; bias_f (16 blocks) -------
__global__ __launch_bounds__(256) void k2_pre(const float* __restrict__ Wo,
                                              const float* __restrict__ Mh,
                                              const float* __restrict__ C_w,
                                              const float* __restrict__ C_b,
                                              const float* __restrict__ a_state,
                                              unsigned short* __restrict__ Wb,
                                              float* __restrict__ bias_f){
  const int blk = blockIdx.x, tid = threadIdx.x;
  if (blk < 1024){
    const int e = blk, h = tid >> 4, dp0 = (tid & 15)*4;
    const float* wo = Wo + (size_t)e*1024 + h*64;
    const float* mh = Mh + (size_t)h*4096 + dp0;
    float ax=0.f, ay=0.f, az=0.f, aw=0.f;
    #pragma unroll 8
    for (int d = 0; d < 64; ++d){
      float c = wo[d];
      float4 m4 = *(const float4*)&mh[d*64];
      ax += c*m4.x; ay += c*m4.y; az += c*m4.z; aw += c*m4.w;
    }
    uint2 pk = make_uint2(f2bf(ax) | (f2bf(ay)<<16), f2bf(az) | (f2bf(aw)<<16));
    *(uint2*)&Wb[(size_t)e*1024 + h*64 + dp0] = pk;
  } else {
    int o = (blk - 1024)*256 + tid;       // [b][f]
    int b = o >> 10, f = o & 1023;
    int h = f >> 6, d = f & 63;
    const float* cw = C_w + (size_t)(h*64 + d)*64;
    const float* as = a_state + (size_t)(h*4 + b)*64;
    float a0=C_b[h*64+d], a1=0.f, a2=0.f, a3=0.f;
    #pragma unroll 4
    for (int s = 0; s < 64; s += 4){
      a0 += cw[s]*as[s]; a1 += cw[s+1]*as[s+1];
      a2 += cw[s+2]*as[s+2]; a3 += cw[s+3]*as[s+3];
    }
    bias_f[o] = (a0+a1)+(a2+a3);
  }
}

// ---------------- K3: const[b][e] = Wo[e][:] . bias_f[b][:] + bo[e]  (64 blocks) -----
__global__ __launch_bounds__(64) void k3_const(const float* __restrict__ Wo,
                                               const float* __restrict__ bo,
                                               const float* __restrict__ bias_f,
                                               float* __restrict__ constb){
  const int blk = blockIdx.x, tid = threadIdx.x;
  const int b = blk >> 4, e = (blk & 15)*64 + tid;
  const float4* wo = (const float4*)(Wo + (size_t)e*1024);
  const float4* bf = (const float4*)(bias_f + (size_t)b*1024);
  float ax=0.f, ay=0.f, az=0.f, aw=0.f;
  for (int f4 = 0; f4 < 256; ++f4){
    float4 w = wo[f4], v = bf[f4];
    ax += w.x*v.x; ay += w.y*v.y; az += w.z*v.z; aw += w.w*v.w;
  }
  constb[b*1024 + e] = bo[e] + ((ax+ay)+(az+aw));
}

// ---------------- K4: new_state (MFMA, swapped operands) + emit xb=bf16(x) -----------
// grid: b(4) x h(16) x tb(32) = 2048 blocks, 256 thr, tile 128(t) x 64(s)
__global__ __launch_bounds__(256) void k4_ns(const float* __restrict__ x,
                                             const unsigned short* __restrict__ smB,
                                             const float* __restrict__ a_state,
                                             unsigned short* __restrict__ xb,
                                             float* __restrict__ out2){
  __shared__ alignas(16) unsigned short Xs[128*72];
  __shared__ alignas(16) unsigned short Ss[64*72];
  const int lin = blockIdx.x;
  const int tb = lin & 31, h = (lin >> 5) & 15, b = lin >> 9;
  const int tid = threadIdx.x;
  const int lane = tid & 63, w = tid >> 6;
  const int l15 = lane & 15, l4 = lane >> 4;

  { // stage smB[h] -> Ss (row stride 72 shorts), 16B granules
    const unsigned short* src = smB + (size_t)h*4096;
    #pragma unroll
    for (int cc = 0; cc < 2; ++cc){
      int c = tid*2 + cc;                  // 512 cells of 8 shorts
      int s = c >> 3, seg = c & 7;
      *(uint4*)&Ss[s*72 + seg*8] = *(const uint4*)&src[s*64 + seg*8];
    }
  }
  { // stage x slice -> Xs bf16 (stride 72) and xb global (16B granules)
    const int row0 = b*Tz + tb*128;
    #pragma unroll
    for (int it = 0; it < 4; ++it){
      int id = it*256 + tid;               // 1024 chunks of 8 floats
      int r = id >> 3, c8 = id & 7;
      const float* px = x + (size_t)(row0 + r)*1024 + h*64 + c8*8;
      float4 v0 = *(const float4*)px, v1 = *(const float4*)(px + 4);
      uint4 pk;
      pk.x = f2bf(v0.x) | (f2bf(v0.y)<<16);
      pk.y = f2bf(v0.z) | (f2bf(v0.w)<<16);
      pk.z = f2bf(v1.x) | (f2bf(v1.y)<<16);
      pk.w = f2bf(v1.z) | (f2bf(v1.w)<<16);
      *(uint4*)&Xs[r*72 + c8*8] = pk;
      *(uint4*)(xb + (size_t)(row0 + r)*1024 + h*64 + c8*8) = pk;
    }
  }
  __syncthreads();

  // acc[i][j]: swapped layout -> D rows = s (regs), D cols = t (l15)
  f32x4 acc[2][4];
  #pragma unroll
  for (int j = 0; j < 4; ++j){
    float4 as4 = *(const float4*)&a_state[(h*4 + b)*64 + j*16 + l4*4];
    f32x4 a0; a0[0]=as4.x; a0[1]=as4.y; a0[2]=as4.z; a0[3]=as4.w;
    acc[0][j] = a0; acc[1][j] = a0;
  }
  #pragma unroll
  for (int kk = 0; kk < 2; ++kk){
    short8 a[2], bb[4];
    #pragma unroll
    for (int i = 0; i < 2; ++i)
      a[i] = *(const short8*)(&Xs[(w*32 + i*16 + l15)*72 + kk*32 + l4*8]);
    #pragma unroll
    for (int j = 0; j < 4; ++j)
      bb[j] = *(const short8*)(&Ss[(j*16 + l15)*72 + kk*32 + l4*8]);
    #pragma unroll
    for (int i = 0; i < 2; ++i)
      #pragma unroll
      for (int j = 0; j < 4; ++j)
        acc[i][j] = __builtin_amdgcn_mfma_f32_16x16x32_bf16(bb[j], a[i], acc[i][j], 0, 0, 0);
  }
  // store: out2[h][b][t][s], thread writes float4 along s
  const size_t base = (size_t)h*1048576 + ((size_t)b*4096 + tb*128)*64;
  #pragma unroll
  for (int i = 0; i < 2; ++i)
    #pragma unroll
    for (int j = 0; j < 4; ++j){
      float4 o = make_float4(acc[i][j][0], acc[i][j][1], acc[i][j][2], acc[i][j][3]);
      *(float4*)(out2 + base + (size_t)(w*32 + i*16 + l15)*64 + j*16 + l4*4) = o;
    }
}

// ---------------- K5: out = xb @ Wb^T + const -----------------------------------------
// 256x256 tile, BK=32, 512 thr (8 waves 2Mx4N), 4 LDS buffers, counted vmcnt(8),
// XOR-swizzled LDS: slot16 = (r*4+g) ^ (r&7)  (inverse applied on global source).
__global__ __launch_bounds__(512, 2) void k5_gemm(const unsigned short* __restrict__ xb,
                                                  const unsigned short* __restrict__ Wb,
                                                  const float* __restrict__ constb,
                                                  float* __restrict__ out){
  __shared__ alignas(16) unsigned short lds[4][2][8192];   // [buf][A/B][256 rows x 32 bf16]
  const int blk = blockIdx.x;
  const int swz = (blk & 7)*32 + (blk >> 3);     // 256 blocks, 8 XCD chunks of 32
  const int bm = (swz >> 2)*256, bn = (swz & 3)*256;
  const int tid = threadIdx.x;
  const int lane = tid & 63, w = tid >> 6;       // 8 waves
  const int l15 = lane & 15, l4 = lane >> 4;
  const int wr = w >> 2, wc = w & 3;             // 2 (M) x 4 (N)

  // staging source mapping: linear slot L -> logical (row r, 16B-seg g)
  const unsigned short* srcA[2];
  const unsigned short* srcB[2];
  #pragma unroll
  for (int q = 0; q < 2; ++q){
    int L = q*512 + w*64 + lane;
    int b = ((L>>2)&1) ^ ((L>>4)&1);
    int r = (L>>3)*2 + b;
    int g = (L&3) ^ ((((L>>3)&1)<<1) | b);
    srcA[q] = xb + (size_t)(bm + r)*1024 + g*8;
    srcB[q] = Wb + (size_t)(bn + r)*1024 + g*8;
  }
  const int dstoff = w*64*8;                      // shorts; + q*4096
  const int lane_off = ((l15*4 + l4) ^ (l15 & 7))*8;  // swizzled frag offset (shorts)

  // prologue: stage tiles 0,1,2 (12 GLL/thread)
  #pragma unroll
  for (int t = 0; t < 3; ++t){
    #pragma unroll
    for (int q = 0; q < 2; ++q) GLL16(srcA[q] + t*32, &lds[t][0][q*4096 + dstoff]);
    #pragma unroll
    for (int q = 0; q < 2; ++q) GLL16(srcB[q] + t*32, &lds[t][1][q*4096 + dstoff]);
  }
  asm volatile("s_waitcnt vmcnt(8)" ::: "memory");
  __builtin_amdgcn_s_barrier();
  asm volatile("" ::: "memory");

  f32x4 acc[8][4] = {};

  for (int t = 0; t < 32; ++t){
    const unsigned short* At = &lds[t & 3][0][0];
    const unsigned short* Bt = &lds[t & 3][1][0];
    const int ts = (t + 3) & 3;
    short8 bfr[4], afr[4];
    // ---- phase A: B-frags + A-frags 0..3, stage A of tile t+3, 16 MFMA
    #pragma unroll
    for (int j = 0; j < 4; ++j)
      bfr[j] = *(const short8*)(Bt + (wc*64 + j*16)*32 + lane_off);
    #pragma unroll
    for (int i = 0; i < 4; ++i)
      afr[i] = *(const short8*)(At + (wr*128 + i*16)*32 + lane_off);
    if (t < 29){
      #pragma unroll
      for (int q = 0; q < 2; ++q) GLL16(srcA[q] + (t+3)*32, &lds[ts][0][q*4096 + dstoff]);
    }
    __builtin_amdgcn_s_setprio(1);
    #pragma unroll
    for (int i = 0; i < 4; ++i)
      #pragma unroll
      for (int j = 0; j < 4; ++j)
        acc[i][j] = __builtin_amdgcn_mfma_f32_16x16x32_bf16(bfr[j], afr[i], acc[i][j], 0, 0, 0);
    __builtin_amdgcn_s_setprio(0);
    // ---- phase B: A-frags 4..7, stage B of tile t+3, 16 MFMA
    #pragma unroll
    for (int i = 0; i < 4; ++i)
      afr[i] = *(const short8*)(At + (wr*128 + (4 + i)*16)*32 + lane_off);
    if (t < 29){
      #pragma unroll
      for (int q = 0; q < 2; ++q) GLL16(srcB[q] + (t+3)*32, &lds[ts][1][q*4096 + dstoff]);
    }
    __builtin_amdgcn_s_setprio(1);
    #pragma unroll
    for (int i = 0; i < 4; ++i)
      #pragma unroll
      for (int j = 0; j < 4; ++j)
        acc[4+i][j] = __builtin_amdgcn_mfma_f32_16x16x32_bf16(bfr[j], afr[i], acc[4+i][j], 0, 0, 0);
    __builtin_amdgcn_s_setprio(0);
    // ---- tile boundary: counted vmcnt (tiles t+2,t+3 stay in flight), barrier
    if (t < 29)       asm volatile("s_waitcnt vmcnt(8)" ::: "memory");
    else if (t == 29) asm volatile("s_waitcnt vmcnt(4)" ::: "memory");
    else if (t == 30) asm volatile("s_waitcnt vmcnt(0)" ::: "memory");
    if (t < 31){
      __builtin_amdgcn_s_barrier();
      asm volatile("" ::: "memory");
    }
  }

  // epilogue: D cols(l15)=t-row, regs(l4*4+q)=e-col (same mapping as verified R1 k5)
  const int bb = bm >> 12;
  #pragma unroll
  for (int j = 0; j < 4; ++j){
    int n0 = bn + wc*64 + j*16 + l4*4;
    float4 cv = *(const float4*)&constb[bb*1024 + n0];
    #pragma unroll
    for (int i = 0; i < 8; ++i){
      int trow = bm + wr*128 + i*16 + l15;
      float4 o = make_float4(acc[i][j][0] + cv.x, acc[i][j][1] + cv.y,
                             acc[i][j][2] + cv.z, acc[i][j][3] + cv.w);
      *(float4*)(out + (size_t)trow*1024 + n0) = o;
    }
  }
}

extern "C" void kernel_launch(void* const* d_in, const int* in_sizes, int n_in,
                              void* d_out, int out_size, void* d_ws, size_t ws_size,
                              hipStream_t stream){
  const float* x     = (const float*)d_in[0];
  const float* state = (const float*)d_in[1];
  const float* A_w   = (const float*)d_in[2];
  const float* A_b   = (const float*)d_in[3];
  const float* C_w   = (const float*)d_in[4];
  const float* C_b   = (const float*)d_in[5];
  const float* sm    = (const float*)d_in[6];
  const float* Wo    = (const float*)d_in[7];
  const float* bo    = (const float*)d_in[8];
  float* out  = (float*)d_out;
  float* out2 = out + (size_t)MTz*Ez;

  char* ws = (char*)d_ws;
  float* a_state          = (float*)(ws + 0);          //  16 KiB
  float* Mh               = (float*)(ws + 16384);      // 256 KiB
  float* bias_f           = (float*)(ws + 278528);     //  16 KiB
  float* constb           = (float*)(ws + 294912);     //  16 KiB
  unsigned short* smB     = (unsigned short*)(ws + 311296);   // 128 KiB
  unsigned short* Wb      = (unsigned short*)(ws + 442368);   //   2 MiB
  unsigned short* xb      = (unsigned short*)(ws + 2539520);  //  32 MiB

  k1_pre<<<64, 256, 0, stream>>>(state, A_w, A_b, C_w, sm, a_state, Mh, smB);
  k2_pre<<<1040, 256, 0, stream>>>(Wo, Mh, C_w, C_b, a_state, Wb, bias_f);
  k3_const<<<64, 64, 0, stream>>>(Wo, bo, bias_f, constb);
  k4_ns<<<2048, 256, 0, stream>>>(x, smB, a_state, xb, out2);
  k5_gemm<<<256, 512, 0, stream>>>(xb, Wb, constb, out);
}